// Round 9
// baseline (65.839 us; speedup 1.0000x reference)
//
#include <hip/hip_runtime.h>

#define DIM 4096
#define R 8
// ws layout: G (8x8) at ws[0..63]; P (4096 x 8) at ws+64
#define P_OFF 64

// async 16B global->LDS (gfx950). LDS dest is wave-uniform base; HW adds
// lane*16. Source is per-lane.
#define GLOAD_LDS16(g, l)                                     \
    __builtin_amdgcn_global_load_lds(                         \
        (const __attribute__((address_space(1))) void*)(g),   \
        (__attribute__((address_space(3))) void*)(l), 16, 0, 0)

// ---------------------------------------------------------------------------
// K1: blocks 0,1 = Gram rows 0..3 / 4..7 (early-return path, proven R6).
// Blocks 2..1025: P[row][:] = W[row,:] @ A for 4 rows. W rows are staged
// into LDS via async global_load_lds (deep VMEM queue, no VGPR pressure —
// R7/R8 showed the compiler caps VGPR at 52 and serializes register loads).
// ---------------------------------------------------------------------------
__global__ __launch_bounds__(256, 2) void dot_kernel(const float* __restrict__ W,
                                                     const float* __restrict__ A,
                                                     float* __restrict__ G,
                                                     float* __restrict__ P) {
    __shared__ float wl[4 * DIM];   // 64 KB: 4 staged W rows
    __shared__ float red[4][32];
    const int t = threadIdx.x;
    const int wave = t >> 6, lane = t & 63;
    const int bid = blockIdx.x;
    const float4* A4 = (const float4*)A;

    if (bid < 2) {
        // ---- Gram path: block 0 -> G rows 0..3, block 1 -> rows 4..7
        const int hi = bid * 4;
        float p[4][R];
#pragma unroll
        for (int r = 0; r < 4; ++r)
#pragma unroll
            for (int k = 0; k < R; ++k) p[r][k] = 0.f;

        for (int it = 0; it < DIM / 256; ++it) {
            const int j = it * 256 + t;
            float4 alo = A4[j * 2 + 0];
            float4 ahi = A4[j * 2 + 1];
            float u[R] = {alo.x, alo.y, alo.z, alo.w, ahi.x, ahi.y, ahi.z, ahi.w};
            float wv0 = hi ? u[4] : u[0];
            float wv1 = hi ? u[5] : u[1];
            float wv2 = hi ? u[6] : u[2];
            float wv3 = hi ? u[7] : u[3];
#pragma unroll
            for (int k = 0; k < R; ++k) {
                p[0][k] += wv0 * u[k];
                p[1][k] += wv1 * u[k];
                p[2][k] += wv2 * u[k];
                p[3][k] += wv3 * u[k];
            }
        }

#pragma unroll
        for (int r = 0; r < 4; ++r)
#pragma unroll
            for (int k = 0; k < R; ++k) {
                float v = p[r][k];
#pragma unroll
                for (int off = 32; off >= 1; off >>= 1) v += __shfl_xor(v, off, 64);
                p[r][k] = v;
            }

#pragma unroll
        for (int i = 0; i < 32; ++i)
            if (lane == i) red[wave][i] = p[i / R][i % R];
        __syncthreads();

        if (t < 32) {
            float v = red[0][t] + red[1][t] + red[2][t] + red[3][t];
            G[(hi + (t >> 3)) * 8 + (t & 7)] = v;
        }
        return;
    }

    const int row0 = (bid - 2) * 4;

    // ---- async stage: wave w stages W row (row0+w) -> wl[w*DIM..]
    // 16 back-to-back 1KB wave-issues => 16KB in flight per wave.
    {
        const float* gbase = W + (size_t)(row0 + wave) * DIM + lane * 4;
        float* lbase = &wl[wave * DIM];
#pragma unroll
        for (int it = 0; it < 16; ++it)
            GLOAD_LDS16(gbase + it * 256, lbase + it * 256);
    }
    asm volatile("s_waitcnt vmcnt(0)" ::: "memory");
    __syncthreads();

    // ---- compute: thread t owns cols c0 = p*1024 + 4t per pass (4 passes).
    // A fragment (8 float4) in regs per pass; W from LDS (contiguous b128).
    float acc[4][R];
#pragma unroll
    for (int r = 0; r < 4; ++r)
#pragma unroll
        for (int k = 0; k < R; ++k) acc[r][k] = 0.f;

    const float4* wl4 = (const float4*)wl;
#pragma unroll
    for (int p = 0; p < 4; ++p) {
        const int c0 = p * 1024 + t * 4;
        float4 alo[4], ahi[4];
#pragma unroll
        for (int jj = 0; jj < 4; ++jj) {
            alo[jj] = A4[(c0 + jj) * 2 + 0];
            ahi[jj] = A4[(c0 + jj) * 2 + 1];
        }
#pragma unroll
        for (int r = 0; r < 4; ++r) {
            float4 wv = wl4[r * (DIM / 4) + p * 256 + t];
#pragma unroll
            for (int jj = 0; jj < 4; ++jj) {
                const float wf = ((const float*)&wv)[jj];
                acc[r][0] += wf * alo[jj].x; acc[r][1] += wf * alo[jj].y;
                acc[r][2] += wf * alo[jj].z; acc[r][3] += wf * alo[jj].w;
                acc[r][4] += wf * ahi[jj].x; acc[r][5] += wf * ahi[jj].y;
                acc[r][6] += wf * ahi[jj].z; acc[r][7] += wf * ahi[jj].w;
            }
        }
    }

    // ---- reduce (R6-proven tail): wave butterfly + cross-wave LDS
#pragma unroll
    for (int r = 0; r < 4; ++r)
#pragma unroll
        for (int k = 0; k < R; ++k) {
            float v = acc[r][k];
#pragma unroll
            for (int off = 32; off >= 1; off >>= 1) v += __shfl_xor(v, off, 64);
            acc[r][k] = v;
        }

#pragma unroll
    for (int i = 0; i < 32; ++i)
        if (lane == i) red[wave][i] = acc[i / R][i % R];
    __syncthreads();

    if (t < 32) {
        float v = red[0][t] + red[1][t] + red[2][t] + red[3][t];
        P[(size_t)(row0 + (t >> 3)) * R + (t & 7)] = v;
    }
}

// ---------------------------------------------------------------------------
// K2: out = W - (2 P G^{-1}) . A^T.  2048 blocks x 256 threads (R4-proven).
// Wave 0 inverts G (8x8 Gauss-Jordan) hidden under A-fragment loads.
// ---------------------------------------------------------------------------
__global__ __launch_bounds__(256, 4) void apply_kernel(const float* __restrict__ W,
                                                       const float* __restrict__ A,
                                                       const float* __restrict__ G,
                                                       const float* __restrict__ P,
                                                       float* __restrict__ out) {
    __shared__ float sb[64];       // Sinv = G^{-1}
    __shared__ float tsh[32][8];

    const int t = threadIdx.x;
    const int wave = t >> 6, lane = t & 63;
    const int bid = blockIdx.x;
    const int tr = bid >> 4;        // 128 row-tiles of 32
    const int tc = bid & 15;        // 16 col-tiles of 256
    const int c4 = tc * 64 + lane;  // float4 column index [0,1024)

    const float4* A4 = (const float4*)A;
    const float4* W4 = (const float4*)W;
    float4* O4 = (float4*)out;

    // issue A-fragment loads first (independent, hides the GJ below)
    float4 alo[4], ahi[4];
#pragma unroll
    for (int jj = 0; jj < 4; ++jj) {
        const int j = c4 * 4 + jj;
        alo[jj] = A4[j * 2 + 0];
        ahi[jj] = A4[j * 2 + 1];
    }

    if (wave == 0) {
        const int r_ = lane >> 3, c_ = lane & 7;
        float M = G[lane];
        float E = (r_ == c_) ? 1.f : 0.f;
        // Gauss-Jordan, no pivoting (G is SPD, kappa ~ 1)
#pragma unroll
        for (int k = 0; k < R; ++k) {
            float piv  = __shfl(M, k * 8 + k, 64);
            float pinv = 1.0f / piv;
            float Mkc  = __shfl(M, k * 8 + c_, 64) * pinv;
            float Ekc  = __shfl(E, k * 8 + c_, 64) * pinv;
            float Mrk  = __shfl(M, r_ * 8 + k, 64);
            bool  isk  = (r_ == k);
            M = isk ? Mkc : (M - Mrk * Mkc);
            E = isk ? Ekc : (E - Mrk * Ekc);
        }
        sb[lane] = E;
    }
    __syncthreads();

    // one t-value per thread: t[r][k] = 2 * sum_m Sinv[k][m] * P[row][m]
    {
        const int r = t >> 3, k = t & 7;
        const int row = tr * 32 + r;
        float a = 0.f;
#pragma unroll
        for (int m = 0; m < R; ++m) a += sb[k * 8 + m] * P[(size_t)row * R + m];
        tsh[r][k] = 2.0f * a;
    }
    __syncthreads();

    const int lr0 = wave * 8;
#pragma unroll
    for (int rr = 0; rr < 8; ++rr) {
        const int row = tr * 32 + lr0 + rr;
        const float* tv = &tsh[lr0 + rr][0];
        float t0 = tv[0], t1 = tv[1], t2 = tv[2], t3 = tv[3];
        float t4 = tv[4], t5 = tv[5], t6 = tv[6], t7 = tv[7];
        float4 w4 = W4[(size_t)row * (DIM / 4) + c4];
        float o[4];
#pragma unroll
        for (int jj = 0; jj < 4; ++jj) {
            float d = t0 * alo[jj].x + t1 * alo[jj].y +
                      t2 * alo[jj].z + t3 * alo[jj].w +
                      t4 * ahi[jj].x + t5 * ahi[jj].y +
                      t6 * ahi[jj].z + t7 * ahi[jj].w;
            o[jj] = ((const float*)&w4)[jj] - d;
        }
        O4[(size_t)row * (DIM / 4) + c4] = make_float4(o[0], o[1], o[2], o[3]);
    }
}

extern "C" void kernel_launch(void* const* d_in, const int* in_sizes, int n_in,
                              void* d_out, int out_size, void* d_ws, size_t ws_size,
                              hipStream_t stream) {
    const float* W = (const float*)d_in[0];    // [4096][4096] f32
    const float* A = (const float*)d_in[1];    // [4096][8]    f32
    float* out = (float*)d_out;                // [4096][4096] f32
    float* G = (float*)d_ws;                   // 64 floats (8x8 Gram)
    float* P = (float*)d_ws + P_OFF;           // 4096*8 floats

    dot_kernel<<<DIM / 4 + 2, 256, 0, stream>>>(W, A, G, P);
    apply_kernel<<<2048, 256, 0, stream>>>(W, A, G, P, out);
}